// Round 10
// baseline (131.351 us; speedup 1.0000x reference)
//
#include <hip/hip_runtime.h>

#define CC 128
#define HH 56
#define WW 56
#define NK2 9
#define NO 18
#define WSZ 4
#define W64 64
#define NCG 16     // conv channel groups (8 ch each)
#define SCG 8      // sample channel groups (16 ch each)
#define CPG 16

// ws layout:
//  wsA : float [4*56][NCG][NO][W64]  = 16.5 MB
//  wsC : float4 [4][9][56][W64]      = 2.06 MB
//  wsI : uint   [4][9][56][W64]      = 0.52 MB
#define WSA_FLOATS (224L * NCG * NO * W64)
#define WSC_ENTRIES (4L * NK2 * HH * W64)

// ---------------- Kernel A: offset conv, 4 rows/block, weights in LDS ------
// block = (b, h4: 4 rows, cg: 8 ch), 256 thr; wave = 2 channels.
// Weights staged ONCE into LDS (padded to 12 floats/o for 16B alignment),
// read back as wave-uniform 2x ds_read_b128 + b32 (broadcast, conflict-free)
// -> no serialized s_load latency chains. amdgpu_waves_per_eu(4,4) pins the
// VGPR budget to 128 so the compiler cannot repeat R6's spill-at-64-VGPR.
__global__ __launch_bounds__(256)
__attribute__((amdgpu_waves_per_eu(4, 4)))
void conv_partial(
    const float* __restrict__ x,          // [B][C][H][W]
    const float* __restrict__ offset_w,   // [18][128][3][3]
    float* __restrict__ wsA)
{
    const int blk = blockIdx.x;           // (b*14 + h4)*16 + cg
    const int cg  = blk & 15;
    const int bh4 = blk >> 4;
    const int b   = bh4 / 14;
    const int h4  = bh4 - b * 14;
    const int h0  = h4 * 4;
    const int t   = threadIdx.x;
    const int lane = t & 63;
    const int wv  = __builtin_amdgcn_readfirstlane(t >> 6);   // 0..3

    __shared__ float s_wt[8][NO][12];     // 6.75 KiB, per-o padded 9->12 (48B)
    __shared__ float s_red[4][NO][64];    // 18 KiB

    const int c0 = cg * 8;

    // stage this block's 8 channels x 18 o's x 9 weights (coalesced reads)
    for (int i = t; i < 8 * NO * 9; i += 256) {
        const int cl  = i / 162;
        const int rem = i - cl * 162;
        const int o   = rem / 9;
        const int j   = rem - o * 9;
        s_wt[cl][o][j] = offset_w[o * (CC * 9) + (c0 + cl) * 9 + j];
    }
    __syncthreads();

    float acc[4][NO];
    #pragma unroll
    for (int r = 0; r < 4; ++r)
        #pragma unroll
        for (int o = 0; o < NO; ++o) acc[r][o] = 0.f;

    if (lane < WW) {
        #pragma unroll
        for (int ci = 0; ci < 2; ++ci) {
            const int cl = wv * 2 + ci;       // wave-uniform
            const int c  = c0 + cl;
            const float* xc = x + ((long)b * CC + c) * HH * WW;

            // rolling 6-row tap buffer: rows h0-1 .. h0+4
            float xr[6][3];
            #pragma unroll
            for (int r6 = 0; r6 < 6; ++r6) {
                const int hy = h0 + r6 - 1;
                float v0 = 0.f, v1 = 0.f, v2 = 0.f;
                if (hy >= 0 && hy < HH) {
                    const float* row = xc + hy * WW;
                    v1 = row[lane];
                    v0 = (lane > 0)      ? row[lane - 1] : 0.f;
                    v2 = (lane < WW - 1) ? row[lane + 1] : 0.f;
                }
                xr[r6][0] = v0; xr[r6][1] = v1; xr[r6][2] = v2;
            }

            #pragma unroll
            for (int o = 0; o < NO; ++o) {
                // wave-uniform LDS read: 2x ds_read_b128 + b32 (broadcast)
                const float* wo = &s_wt[cl][o][0];
                float w9[9];
                #pragma unroll
                for (int j = 0; j < 9; ++j) w9[j] = wo[j];
                #pragma unroll
                for (int ky = 0; ky < 3; ++ky)
                    #pragma unroll
                    for (int kx = 0; kx < 3; ++kx) {
                        const float wf = w9[ky * 3 + kx];
                        #pragma unroll
                        for (int r = 0; r < 4; ++r)
                            acc[r][o] += wf * xr[r + ky][kx];
                    }
            }
        }
    }

    // cross-wave reduce: 1 row per round, pure shift/mask indexing
    const float* sr = (const float*)s_red;    // 4 slices of 1152
    #pragma unroll
    for (int round = 0; round < 4; ++round) {
        #pragma unroll
        for (int o = 0; o < NO; ++o) s_red[wv][o][lane] = acc[round][o];
        __syncthreads();
        const int bh = b * HH + h0 + round;
        float* dst = wsA + ((long)bh * NCG + cg) * (NO * W64);
        for (int s = t; s < NO * W64; s += 256)
            dst[s] = sr[s] + sr[1152 + s] + sr[2 * 1152 + s] + sr[3 * 1152 + s];
        __syncthreads();
    }
}

// ---------------- Kernel A2: reduce 16 partials -> bilinear coefs ----------
__global__ __launch_bounds__(64) void coef_kernel(
    const float* __restrict__ wsA,
    const float* __restrict__ offset_b,
    float4* __restrict__ wsC,
    unsigned* __restrict__ wsI)
{
    const int blk = blockIdx.x;          // bh*9 + k2
    const int k2  = blk % NK2;
    const int bh  = blk / NK2;
    const int b   = bh / HH;
    const int h   = bh - b * HH;
    const int w   = threadIdx.x;         // 0..63

    const float* base = wsA + (long)bh * (NCG * NO * W64);
    float dy = offset_b[2 * k2];
    float dx = offset_b[2 * k2 + 1];
    #pragma unroll
    for (int g = 0; g < NCG; ++g) {
        dy += base[g * (NO * W64) + (2 * k2) * W64 + w];
        dx += base[g * (NO * W64) + (2 * k2 + 1) * W64 + w];
    }

    const float yc = dy + 0.5f + (float)(k2 / 3);
    const float xc = dx + 0.5f + (float)(k2 % 3);
    const float y0 = floorf(yc), x0f = floorf(xc);
    const float fy = yc - y0, fx = xc - x0f;
    const int yi = (int)y0, xi = (int)x0f;
    float cf[4]; int id[4];
    #pragma unroll
    for (int q = 0; q < 4; ++q) {
        const int oy = q >> 1, ox = q & 1;
        const int yy = yi + oy, xx = xi + ox;
        float c2 = (oy ? fy : 1.f - fy) * (ox ? fx : 1.f - fx);
        const bool valid = (yy >= 0) && (yy < WSZ) && (xx >= 0) && (xx < WSZ);
        cf[q] = valid ? c2 : 0.f;
        const int yyc = yy < 0 ? 0 : (yy > 3 ? 3 : yy);
        const int xxc = xx < 0 ? 0 : (xx > 3 ? 3 : xx);
        id[q] = yyc * 4 + xxc;
    }
    const long oidx = ((long)(b * NK2 + k2) * HH + h) * W64 + w;
    wsC[oidx] = make_float4(cf[0], cf[1], cf[2], cf[3]);
    wsI[oidx] = (unsigned)(id[0] | (id[1] << 4) | (id[2] << 8) | (id[3] << 12));
}

// ---------------- Kernel B: weight sampling + patch multiply ---------------
__global__ __launch_bounds__(256) void sample_kernel(
    const float* __restrict__ x,        // [B][C][H][W]
    const float* __restrict__ weight,   // [C][16]
    const float4* __restrict__ wsC,
    const unsigned* __restrict__ wsI,
    float* __restrict__ out)            // [B][C][H][W]
{
    const int blk = blockIdx.x;          // bh*8 + cg
    const int bh  = blk >> 3;
    const int cg  = blk & 7;
    const int b   = bh / HH;
    const int h   = bh - b * HH;
    const int t   = threadIdx.x;
    const int lane = t & 63;
    const int wv  = __builtin_amdgcn_readfirstlane(t >> 6);  // 0..3

    __shared__ float s_wT[16][20];       // [j][c], pad 16->20
    if (t < 256) {
        const int j = t >> 4, cl = t & 15;
        s_wT[j][cl] = weight[(cg * CPG + cl) * 16 + j];
    }
    __syncthreads();

    if (lane >= WW) return;
    const int w = lane;
    const int cl0 = wv * 4;

    float4 cf[NK2]; unsigned pk[NK2];
    const long cidx0 = ((long)b * NK2 * HH + h) * W64 + w;
    #pragma unroll
    for (int k2 = 0; k2 < NK2; ++k2) {
        cf[k2] = wsC[cidx0 + (long)k2 * HH * W64];
        pk[k2] = wsI[cidx0 + (long)k2 * HH * W64];
    }

    float xv[4][9];
    #pragma unroll
    for (int u = 0; u < 4; ++u) {
        const int c = cg * CPG + cl0 + u;
        const float* xc = x + ((long)b * CC + c) * HH * WW;
        #pragma unroll
        for (int ky = 0; ky < 3; ++ky) {
            const int hy = h + ky - 1;
            #pragma unroll
            for (int kx = 0; kx < 3; ++kx) {
                const int wx = w + kx - 1;
                float v = 0.f;
                if (hy >= 0 && hy < HH && wx >= 0 && wx < WW)
                    v = xc[hy * WW + wx];
                xv[u][ky * 3 + kx] = v;
            }
        }
    }

    float res[4] = {0.f, 0.f, 0.f, 0.f};
    #pragma unroll
    for (int k2 = 0; k2 < NK2; ++k2) {
        const unsigned p = pk[k2];
        const float4 W0 = *(const float4*)&s_wT[p & 15][cl0];
        const float4 W1 = *(const float4*)&s_wT[(p >> 4) & 15][cl0];
        const float4 W2 = *(const float4*)&s_wT[(p >> 8) & 15][cl0];
        const float4 W3 = *(const float4*)&s_wT[(p >> 12) & 15][cl0];
        const float4 c4 = cf[k2];
        res[0] += (c4.x * W0.x + c4.y * W1.x + c4.z * W2.x + c4.w * W3.x) * xv[0][k2];
        res[1] += (c4.x * W0.y + c4.y * W1.y + c4.z * W2.y + c4.w * W3.y) * xv[1][k2];
        res[2] += (c4.x * W0.z + c4.y * W1.z + c4.z * W2.z + c4.w * W3.z) * xv[2][k2];
        res[3] += (c4.x * W0.w + c4.y * W1.w + c4.z * W2.w + c4.w * W3.w) * xv[3][k2];
    }

    #pragma unroll
    for (int u = 0; u < 4; ++u) {
        const int c = cg * CPG + cl0 + u;
        out[(((long)b * CC + c) * HH + h) * WW + w] = res[u];
    }
}

extern "C" void kernel_launch(void* const* d_in, const int* in_sizes, int n_in,
                              void* d_out, int out_size, void* d_ws, size_t ws_size,
                              hipStream_t stream) {
    const float* x        = (const float*)d_in[0];
    const float* offset_w = (const float*)d_in[1];
    const float* offset_b = (const float*)d_in[2];
    const float* weight   = (const float*)d_in[3];
    float* out = (float*)d_out;

    char* p = (char*)d_ws;
    float*    wsA = (float*)p;                          p += WSA_FLOATS * 4;
    float4*   wsC = (float4*)p;                         p += WSC_ENTRIES * 16;
    unsigned* wsI = (unsigned*)p;

    conv_partial <<<4 * 14 * NCG, 256, 0, stream>>>(x, offset_w, wsA);
    coef_kernel  <<<224 * NK2, 64, 0, stream>>>(wsA, offset_b, wsC, wsI);
    sample_kernel<<<224 * SCG, 256, 0, stream>>>(x, weight, wsC, wsI, out);
}

// Round 11
// 96.030 us; speedup vs baseline: 1.3678x; 1.3678x over previous
//
#include <hip/hip_runtime.h>

#define CC 128
#define HH 56
#define WW 56
#define NK2 9
#define NO 18
#define WSZ 4
#define W64 64
#define SCG 8
#define CPG 16

typedef __attribute__((ext_vector_type(8))) short short8;
typedef __attribute__((ext_vector_type(4))) float f32x4;

// ws layout:
//  wsW : ushort [9][2][4][64][8]  = 36864 bf16 = 73,728 B (A-fragments)
//  wsC : float4 [4][9][56][64]    = 2.06 MB
//  wsI : uint   [4][9][56][64]    = 0.52 MB
#define WSW_SHORTS  (9L * 2 * 4 * 64 * 8)
#define WSC_ENTRIES (4L * NK2 * HH * W64)

__device__ __forceinline__ unsigned short f2bf(float f) {
    unsigned u = __builtin_bit_cast(unsigned, f);
    u = u + 0x7fffu + ((u >> 16) & 1u);       // RNE
    return (unsigned short)(u >> 16);
}

// ---- Kernel 0: pack offset_w into MFMA A-fragment order (bf16) ------------
// frag elem e = (((k9*2 + mt)*4 + kt)*64 + lane)*8 + j
// A[m=lane&15 -> o][k=(lane>>4)*8+j -> c within ktile], per (ky,kx)=k9.
__global__ __launch_bounds__(256) void prep_afrag(
    const float* __restrict__ offset_w,     // [18][128][3][3]
    unsigned short* __restrict__ wsW)
{
    const int e = blockIdx.x * 256 + threadIdx.x;
    if (e >= (int)WSW_SHORTS) return;
    const int j    = e & 7;
    const int lane = (e >> 3) & 63;
    const int kt   = (e >> 9) & 3;
    const int mt   = (e >> 11) & 1;
    const int k9   = e >> 12;                // 0..8 = ky*3+kx
    const int o = mt * 16 + (lane & 15);
    const int c = kt * 32 + (lane >> 4) * 8 + j;
    float v = 0.f;
    if (o < NO) v = offset_w[(o * CC + c) * 9 + k9];
    wsW[e] = f2bf(v);
}

// ---- Kernel A: offset conv via MFMA shift-GEMM + fused coefs --------------
// block = (b,h), 512 thr = 8 waves; wave = (ntile: 16 px, mtile: 16 o's).
// x staged once as bf16 [3 rows][58 cols][128 ch] (c-contiguous, stride 272B
// = 17*16 -> aligned ds_read_b128). 9 shift-GEMMs of K=128: B-frag = LDS read
// at col+kx. D (C-layout col=lane&15,row=(lane>>4)*4+reg, m89-verified) ->
// s_off -> bilinear coefs written directly (wsA + coef_kernel eliminated).
__global__ __launch_bounds__(512) void conv_mfma(
    const float* __restrict__ x,            // [B][C][H][W]
    const unsigned short* __restrict__ wsW, // A-fragments
    const float* __restrict__ offset_b,     // [18]
    float4* __restrict__ wsC,
    unsigned* __restrict__ wsI)
{
    const int blk = blockIdx.x;             // b*56 + h
    const int b = blk / HH;
    const int h = blk - b * HH;
    const int t = threadIdx.x;
    const int lane = t & 63;
    const int wv = t >> 6;                  // 0..7

    __shared__ unsigned short s_xb[3][58][136];  // 47.3 KiB bf16
    __shared__ float s_off[NO][W64];             // 4.5 KiB

    // stage x rows h-1..h+1, all 128 ch, cols -1..56 (zero-padded), bf16
    for (int i = t; i < 3 * CC * 58; i += 512) {
        const int r   = i / (CC * 58);
        const int rem = i - r * (CC * 58);
        const int c   = rem / 58;
        const int col = rem - c * 58;
        const int hy = h + r - 1;
        const int w  = col - 1;
        float v = 0.f;
        if (hy >= 0 && hy < HH && w >= 0 && w < WW)
            v = x[(((long)b * CC + c) * HH + hy) * WW + w];
        s_xb[r][col][c] = f2bf(v);
    }
    __syncthreads();

    const int nt  = wv & 3;                 // n-tile: px 16*nt..+15
    const int mt  = wv >> 2;                // m-tile: o 16*mt..+15
    const int q   = lane >> 4;
    const int n15 = lane & 15;

    f32x4 acc = {0.f, 0.f, 0.f, 0.f};
    #pragma unroll
    for (int k9 = 0; k9 < 9; ++k9) {
        const int ky = k9 / 3, kx = k9 - ky * 3;
        int col = nt * 16 + n15 + kx;       // shifted column (px + kx)
        col = col > 57 ? 57 : col;          // pad lanes clamp (discarded)
        const unsigned short* bbase = &s_xb[ky][col][q * 8];
        const unsigned short* abase = wsW + ((long)(k9 * 2 + mt) * 4 * 64 + lane) * 8;
        #pragma unroll
        for (int kt = 0; kt < 4; ++kt) {
            short8 a  = *(const short8*)(abase + kt * 512);
            short8 bf = *(const short8*)(bbase + kt * 32);
            acc = __builtin_amdgcn_mfma_f32_16x16x32_bf16(a, bf, acc, 0, 0, 0);
        }
    }
    // D -> s_off: row o = mt*16 + q*4 + reg; col px = nt*16 + n15
    #pragma unroll
    for (int reg = 0; reg < 4; ++reg) {
        const int o = mt * 16 + q * 4 + reg;
        if (o < NO) s_off[o][nt * 16 + n15] = acc[reg];
    }
    __syncthreads();

    // fused coef phase: bilinear coefs+indices per (k2, px)
    for (int i = t; i < NK2 * 64; i += 512) {
        const int k2 = i >> 6;
        const int px = i & 63;
        const float dy = s_off[2 * k2][px]     + offset_b[2 * k2];
        const float dx = s_off[2 * k2 + 1][px] + offset_b[2 * k2 + 1];
        const float yc = dy + 0.5f + (float)(k2 / 3);
        const float xc = dx + 0.5f + (float)(k2 % 3);
        const float y0 = floorf(yc), x0f = floorf(xc);
        const float fy = yc - y0, fx = xc - x0f;
        const int yi = (int)y0, xi = (int)x0f;
        float cf[4]; int id[4];
        #pragma unroll
        for (int qq = 0; qq < 4; ++qq) {
            const int oy = qq >> 1, ox = qq & 1;
            const int yy = yi + oy, xx = xi + ox;
            float c2 = (oy ? fy : 1.f - fy) * (ox ? fx : 1.f - fx);
            const bool valid = (yy >= 0) && (yy < WSZ) && (xx >= 0) && (xx < WSZ);
            cf[qq] = valid ? c2 : 0.f;
            const int yyc = yy < 0 ? 0 : (yy > 3 ? 3 : yy);
            const int xxc = xx < 0 ? 0 : (xx > 3 ? 3 : xx);
            id[qq] = yyc * 4 + xxc;
        }
        const long oidx = ((long)(b * NK2 + k2) * HH + h) * W64 + px;
        wsC[oidx] = make_float4(cf[0], cf[1], cf[2], cf[3]);
        wsI[oidx] = (unsigned)(id[0] | (id[1] << 4) | (id[2] << 8) | (id[3] << 12));
    }
}

// ---------------- Kernel B: weight sampling + patch multiply ---------------
// (byte-identical to R7's proven version)
__global__ __launch_bounds__(256) void sample_kernel(
    const float* __restrict__ x,        // [B][C][H][W]
    const float* __restrict__ weight,   // [C][16]
    const float4* __restrict__ wsC,
    const unsigned* __restrict__ wsI,
    float* __restrict__ out)            // [B][C][H][W]
{
    const int blk = blockIdx.x;          // bh*8 + cg
    const int bh  = blk >> 3;
    const int cg  = blk & 7;
    const int b   = bh / HH;
    const int h   = bh - b * HH;
    const int t   = threadIdx.x;
    const int lane = t & 63;
    const int wv  = __builtin_amdgcn_readfirstlane(t >> 6);  // 0..3

    __shared__ float s_wT[16][20];       // [j][c], pad 16->20
    if (t < 256) {
        const int j = t >> 4, cl = t & 15;
        s_wT[j][cl] = weight[(cg * CPG + cl) * 16 + j];
    }
    __syncthreads();

    if (lane >= WW) return;
    const int w = lane;
    const int cl0 = wv * 4;

    float4 cf[NK2]; unsigned pk[NK2];
    const long cidx0 = ((long)b * NK2 * HH + h) * W64 + w;
    #pragma unroll
    for (int k2 = 0; k2 < NK2; ++k2) {
        cf[k2] = wsC[cidx0 + (long)k2 * HH * W64];
        pk[k2] = wsI[cidx0 + (long)k2 * HH * W64];
    }

    float xv[4][9];
    #pragma unroll
    for (int u = 0; u < 4; ++u) {
        const int c = cg * CPG + cl0 + u;
        const float* xc = x + ((long)b * CC + c) * HH * WW;
        #pragma unroll
        for (int ky = 0; ky < 3; ++ky) {
            const int hy = h + ky - 1;
            #pragma unroll
            for (int kx = 0; kx < 3; ++kx) {
                const int wx = w + kx - 1;
                float v = 0.f;
                if (hy >= 0 && hy < HH && wx >= 0 && wx < WW)
                    v = xc[hy * WW + wx];
                xv[u][ky * 3 + kx] = v;
            }
        }
    }

    float res[4] = {0.f, 0.f, 0.f, 0.f};
    #pragma unroll
    for (int k2 = 0; k2 < NK2; ++k2) {
        const unsigned p = pk[k2];
        const float4 W0 = *(const float4*)&s_wT[p & 15][cl0];
        const float4 W1 = *(const float4*)&s_wT[(p >> 4) & 15][cl0];
        const float4 W2 = *(const float4*)&s_wT[(p >> 8) & 15][cl0];
        const float4 W3 = *(const float4*)&s_wT[(p >> 12) & 15][cl0];
        const float4 c4 = cf[k2];
        res[0] += (c4.x * W0.x + c4.y * W1.x + c4.z * W2.x + c4.w * W3.x) * xv[0][k2];
        res[1] += (c4.x * W0.y + c4.y * W1.y + c4.z * W2.y + c4.w * W3.y) * xv[1][k2];
        res[2] += (c4.x * W0.z + c4.y * W1.z + c4.z * W2.z + c4.w * W3.z) * xv[2][k2];
        res[3] += (c4.x * W0.w + c4.y * W1.w + c4.z * W2.w + c4.w * W3.w) * xv[3][k2];
    }

    #pragma unroll
    for (int u = 0; u < 4; ++u) {
        const int c = cg * CPG + cl0 + u;
        out[(((long)b * CC + c) * HH + h) * WW + w] = res[u];
    }
}

extern "C" void kernel_launch(void* const* d_in, const int* in_sizes, int n_in,
                              void* d_out, int out_size, void* d_ws, size_t ws_size,
                              hipStream_t stream) {
    const float* x        = (const float*)d_in[0];
    const float* offset_w = (const float*)d_in[1];
    const float* offset_b = (const float*)d_in[2];
    const float* weight   = (const float*)d_in[3];
    float* out = (float*)d_out;

    char* p = (char*)d_ws;
    unsigned short* wsW = (unsigned short*)p;           p += WSW_SHORTS * 2;
    float4*         wsC = (float4*)p;                   p += WSC_ENTRIES * 16;
    unsigned*       wsI = (unsigned*)p;

    prep_afrag   <<<(int)(WSW_SHORTS / 256), 256, 0, stream>>>(offset_w, wsW);
    conv_mfma    <<<4 * HH, 512, 0, stream>>>(x, wsW, offset_b, wsC, wsI);
    sample_kernel<<<224 * SCG, 256, 0, stream>>>(x, weight, wsC, wsI, out);
}

// Round 12
// 91.609 us; speedup vs baseline: 1.4338x; 1.0483x over previous
//
#include <hip/hip_runtime.h>

#define CC 128
#define HH 56
#define WW 56
#define NK2 9
#define NO 18
#define WSZ 4
#define W64 64

typedef __attribute__((ext_vector_type(8))) short short8;
typedef __attribute__((ext_vector_type(4))) float f32x4;

// ws layout (all 256B-aligned):
//  wsW : ushort [9][2][4][64][8]        = 73,728 B   (MFMA A-fragments)
//  xb  : ushort [4][58][58][128]        = 3,444,736 B (padded channel-last bf16 x)
//  wsC : float4 [4][9][56][64]          = 2,064,384 B
//  wsI : uint   [4][9][56][64]          =   516,096 B
#define WSW_SHORTS  (9L * 2 * 4 * 64 * 8)
#define WSXB_SHORTS (4L * 58 * 58 * 128)
#define WSC_ENTRIES (4L * NK2 * HH * W64)

__device__ __forceinline__ unsigned short f2bf(float f) {
    unsigned u = __builtin_bit_cast(unsigned, f);
    u = u + 0x7fffu + ((u >> 16) & 1u);       // RNE
    return (unsigned short)(u >> 16);
}

// ---- Kernel 0: prep. blocks 0..231: x -> padded channel-last bf16 ---------
//                blocks 232..375: offset_w -> MFMA A-fragments (R11-proven)
__global__ __launch_bounds__(256) void prep(
    const float* __restrict__ x,            // [B][C][H][W]
    const float* __restrict__ offset_w,     // [18][128][3][3]
    unsigned short* __restrict__ xb,
    unsigned short* __restrict__ wsW)
{
    const int blk = blockIdx.x;
    const int t   = threadIdx.x;
    if (blk < 232) {
        // transpose one (b, hp) row: xb[b][hp][wp][c], hp=h+1, wp=w+1
        const int b  = blk / 58;
        const int hp = blk - b * 58;
        const int h  = hp - 1;
        __shared__ unsigned short s[CC][58];   // [c][wp] 14.8 KiB
        if (h >= 0 && h < HH) {
            for (int i = t; i < CC * WW; i += 256) {
                const int c = i / WW, w = i - c * WW;
                s[c][w + 1] = f2bf(x[(((long)b * CC + c) * HH + h) * WW + w]);
            }
        }
        __syncthreads();
        for (int j = t; j < 58 * CC; j += 256) {
            const int wp = j >> 7, c = j & 127;
            unsigned short v = 0;
            if (h >= 0 && h < HH && wp >= 1 && wp <= WW) v = s[c][wp];
            xb[(((long)b * 58 + hp) * 58 + wp) * CC + c] = v;
        }
    } else {
        // A-fragments: e = (((k9*2 + mt)*4 + kt)*64 + lane)*8 + j
        const int e = (blk - 232) * 256 + t;
        if (e >= (int)WSW_SHORTS) return;
        const int j    = e & 7;
        const int lane = (e >> 3) & 63;
        const int kt   = (e >> 9) & 3;
        const int mt   = (e >> 11) & 1;
        const int k9   = e >> 12;              // 0..8 = ky*3+kx
        const int o = mt * 16 + (lane & 15);
        const int c = kt * 32 + (lane >> 4) * 8 + j;
        float v = 0.f;
        if (o < NO) v = offset_w[(o * CC + c) * 9 + k9];
        wsW[e] = f2bf(v);
    }
}

// ---- Kernel A: offset conv via MFMA shift-GEMM, B-frags from global -------
// block = (b,h), 1024 thr = 16 waves: wave = (kh: k9-half, mt, nt).
// No x staging: B-fragment = 16B global load from channel-last xb (L2-hot).
// Partials reduced via 9 KB LDS; coefs fused (R11-proven math).
__global__ __launch_bounds__(1024) void conv_mfma(
    const unsigned short* __restrict__ xb,
    const unsigned short* __restrict__ wsW,
    const float* __restrict__ offset_b,
    float4* __restrict__ wsC,
    unsigned* __restrict__ wsI)
{
    const int blk = blockIdx.x;             // b*56 + h
    const int b = blk / HH;
    const int h = blk - b * HH;
    const int t = threadIdx.x;
    const int lane = t & 63;
    const int wv = t >> 6;                  // 0..15

    __shared__ float s_red[2][NO][W64];     // 9 KiB

    const int nt  = wv & 3;                 // px tile
    const int mt  = (wv >> 2) & 1;          // o tile
    const int kh  = wv >> 3;                // k9 half: 0->[0,5) 1->[5,9)
    const int q   = lane >> 4;
    const int n15 = lane & 15;

    f32x4 acc = {0.f, 0.f, 0.f, 0.f};
    const int k9lo = kh ? 5 : 0;
    const int k9hi = kh ? 9 : 5;
    for (int k9 = k9lo; k9 < k9hi; ++k9) {
        const int ky = k9 / 3, kx = k9 - ky * 3;
        int col = nt * 16 + n15 + kx;       // wp = px + kx (xb pre-padded)
        col = col > 57 ? 57 : col;          // pad lanes clamp (discarded)
        const unsigned short* bbase =
            xb + (((long)b * 58 + (h + ky)) * 58 + col) * CC + q * 8;
        const unsigned short* abase =
            wsW + ((long)(k9 * 2 + mt) * 4 * 64 + lane) * 8;
        #pragma unroll
        for (int kt = 0; kt < 4; ++kt) {
            short8 a  = *(const short8*)(abase + kt * 512);
            short8 bf = *(const short8*)(bbase + kt * 32);
            acc = __builtin_amdgcn_mfma_f32_16x16x32_bf16(a, bf, acc, 0, 0, 0);
        }
    }
    // partials: row o = mt*16 + q*4 + reg; col px = nt*16 + n15
    #pragma unroll
    for (int reg = 0; reg < 4; ++reg) {
        const int o = mt * 16 + q * 4 + reg;
        if (o < NO) s_red[kh][o][nt * 16 + n15] = acc[reg];
    }
    __syncthreads();

    // fused coef phase (576 items)
    if (t < NK2 * 64) {
        const int k2 = t >> 6;
        const int px = t & 63;
        const float dy = s_red[0][2 * k2][px] + s_red[1][2 * k2][px]
                       + offset_b[2 * k2];
        const float dx = s_red[0][2 * k2 + 1][px] + s_red[1][2 * k2 + 1][px]
                       + offset_b[2 * k2 + 1];
        const float yc = dy + 0.5f + (float)(k2 / 3);
        const float xc = dx + 0.5f + (float)(k2 % 3);
        const float y0 = floorf(yc), x0f = floorf(xc);
        const float fy = yc - y0, fx = xc - x0f;
        const int yi = (int)y0, xi = (int)x0f;
        float cf[4]; int id[4];
        #pragma unroll
        for (int qq = 0; qq < 4; ++qq) {
            const int oy = qq >> 1, ox = qq & 1;
            const int yy = yi + oy, xx = xi + ox;
            float c2 = (oy ? fy : 1.f - fy) * (ox ? fx : 1.f - fx);
            const bool valid = (yy >= 0) && (yy < WSZ) && (xx >= 0) && (xx < WSZ);
            cf[qq] = valid ? c2 : 0.f;
            const int yyc = yy < 0 ? 0 : (yy > 3 ? 3 : yy);
            const int xxc = xx < 0 ? 0 : (xx > 3 ? 3 : xx);
            id[qq] = yyc * 4 + xxc;
        }
        const long oidx = ((long)(b * NK2 + k2) * HH + h) * W64 + px;
        wsC[oidx] = make_float4(cf[0], cf[1], cf[2], cf[3]);
        wsI[oidx] = (unsigned)(id[0] | (id[1] << 4) | (id[2] << 8) | (id[3] << 12));
    }
}

// ---- Kernel B: weight sampling + patch multiply, 128-thr blocks -----------
// block = (bh, cg: 8 channels), 2 waves; wave = 4 channels, lane = px.
// 3584 blocks -> ~4 waves/SIMD (vs 1.75 before), same math as R7/R11.
__global__ __launch_bounds__(128) void sample_kernel(
    const float* __restrict__ x,        // [B][C][H][W]
    const float* __restrict__ weight,   // [C][16]
    const float4* __restrict__ wsC,
    const unsigned* __restrict__ wsI,
    float* __restrict__ out)            // [B][C][H][W]
{
    const int blk = blockIdx.x;          // bh*16 + cg
    const int bh  = blk >> 4;
    const int cg  = blk & 15;
    const int b   = bh / HH;
    const int h   = bh - b * HH;
    const int t   = threadIdx.x;
    const int lane = t & 63;
    const int wv  = __builtin_amdgcn_readfirstlane(t >> 6);  // 0..1

    __shared__ float s_wT[16][12];       // [j][c], 8 ch pad->12 (16B-aligned)
    if (t < 128) {
        const int j = t >> 3, cl = t & 7;
        s_wT[j][cl] = weight[(cg * 8 + cl) * 16 + j];
    }
    __syncthreads();

    if (lane >= WW) return;
    const int w = lane;
    const int cl0 = wv * 4;              // 0 or 4

    float4 cf[NK2]; unsigned pk[NK2];
    const long cidx0 = ((long)b * NK2 * HH + h) * W64 + w;
    #pragma unroll
    for (int k2 = 0; k2 < NK2; ++k2) {
        cf[k2] = wsC[cidx0 + (long)k2 * HH * W64];
        pk[k2] = wsI[cidx0 + (long)k2 * HH * W64];
    }

    float xv[4][9];
    #pragma unroll
    for (int u = 0; u < 4; ++u) {
        const int c = cg * 8 + cl0 + u;
        const float* xc = x + ((long)b * CC + c) * HH * WW;
        #pragma unroll
        for (int ky = 0; ky < 3; ++ky) {
            const int hy = h + ky - 1;
            #pragma unroll
            for (int kx = 0; kx < 3; ++kx) {
                const int wx = w + kx - 1;
                float v = 0.f;
                if (hy >= 0 && hy < HH && wx >= 0 && wx < WW)
                    v = xc[hy * WW + wx];
                xv[u][ky * 3 + kx] = v;
            }
        }
    }

    float res[4] = {0.f, 0.f, 0.f, 0.f};
    #pragma unroll
    for (int k2 = 0; k2 < NK2; ++k2) {
        const unsigned p = pk[k2];
        const float4 W0 = *(const float4*)&s_wT[p & 15][cl0];
        const float4 W1 = *(const float4*)&s_wT[(p >> 4) & 15][cl0];
        const float4 W2 = *(const float4*)&s_wT[(p >> 8) & 15][cl0];
        const float4 W3 = *(const float4*)&s_wT[(p >> 12) & 15][cl0];
        const float4 c4 = cf[k2];
        res[0] += (c4.x * W0.x + c4.y * W1.x + c4.z * W2.x + c4.w * W3.x) * xv[0][k2];
        res[1] += (c4.x * W0.y + c4.y * W1.y + c4.z * W2.y + c4.w * W3.y) * xv[1][k2];
        res[2] += (c4.x * W0.z + c4.y * W1.z + c4.z * W2.z + c4.w * W3.z) * xv[2][k2];
        res[3] += (c4.x * W0.w + c4.y * W1.w + c4.z * W2.w + c4.w * W3.w) * xv[3][k2];
    }

    #pragma unroll
    for (int u = 0; u < 4; ++u) {
        const int c = cg * 8 + cl0 + u;
        out[(((long)b * CC + c) * HH + h) * WW + w] = res[u];
    }
}

extern "C" void kernel_launch(void* const* d_in, const int* in_sizes, int n_in,
                              void* d_out, int out_size, void* d_ws, size_t ws_size,
                              hipStream_t stream) {
    const float* x        = (const float*)d_in[0];
    const float* offset_w = (const float*)d_in[1];
    const float* offset_b = (const float*)d_in[2];
    const float* weight   = (const float*)d_in[3];
    float* out = (float*)d_out;

    char* p = (char*)d_ws;
    unsigned short* wsW = (unsigned short*)p;           p += WSW_SHORTS * 2;
    unsigned short* xb  = (unsigned short*)p;           p += WSXB_SHORTS * 2;
    float4*         wsC = (float4*)p;                   p += WSC_ENTRIES * 16;
    unsigned*       wsI = (unsigned*)p;

    prep         <<<232 + 144, 256, 0, stream>>>(x, offset_w, xb, wsW);
    conv_mfma    <<<4 * HH, 1024, 0, stream>>>(xb, wsW, offset_b, wsC, wsI);
    sample_kernel<<<224 * 16, 128, 0, stream>>>(x, weight, wsC, wsI, out);
}

// Round 13
// 89.321 us; speedup vs baseline: 1.4705x; 1.0256x over previous
//
#include <hip/hip_runtime.h>

#define CC 128
#define HH 56
#define WW 56
#define NK2 9
#define NO 18
#define WSZ 4
#define W64 64

typedef __attribute__((ext_vector_type(8))) short short8;
typedef __attribute__((ext_vector_type(4))) float f32x4;

// ws layout:
//  wsW : ushort [9][2][4][64][8] = 73,728 B   (MFMA A-fragments)
//  xb  : ushort [4][58][58][128] = 3,444,736 B (padded channel-last bf16 x)
#define WSW_SHORTS  (9L * 2 * 4 * 64 * 8)
#define WSXB_SHORTS (4L * 58 * 58 * 128)

__device__ __forceinline__ unsigned short f2bf(float f) {
    unsigned u = __builtin_bit_cast(unsigned, f);
    u = u + 0x7fffu + ((u >> 16) & 1u);       // RNE
    return (unsigned short)(u >> 16);
}

// ---- Kernel 0: prep (verbatim R12). blocks 0..231: x -> channel-last bf16;
//                blocks 232..375: offset_w -> MFMA A-fragments.
__global__ __launch_bounds__(256) void prep(
    const float* __restrict__ x,            // [B][C][H][W]
    const float* __restrict__ offset_w,     // [18][128][3][3]
    unsigned short* __restrict__ xb,
    unsigned short* __restrict__ wsW)
{
    const int blk = blockIdx.x;
    const int t   = threadIdx.x;
    if (blk < 232) {
        const int b  = blk / 58;
        const int hp = blk - b * 58;
        const int h  = hp - 1;
        __shared__ unsigned short s[CC][58];
        if (h >= 0 && h < HH) {
            for (int i = t; i < CC * WW; i += 256) {
                const int c = i / WW, w = i - c * WW;
                s[c][w + 1] = f2bf(x[(((long)b * CC + c) * HH + h) * WW + w]);
            }
        }
        __syncthreads();
        for (int j = t; j < 58 * CC; j += 256) {
            const int wp = j >> 7, c = j & 127;
            unsigned short v = 0;
            if (h >= 0 && h < HH && wp >= 1 && wp <= WW) v = s[c][wp];
            xb[(((long)b * 58 + hp) * 58 + wp) * CC + c] = v;
        }
    } else {
        const int e = (blk - 232) * 256 + t;
        if (e >= (int)WSW_SHORTS) return;
        const int j    = e & 7;
        const int lane = (e >> 3) & 63;
        const int kt   = (e >> 9) & 3;
        const int mt   = (e >> 11) & 1;
        const int k9   = e >> 12;
        const int o = mt * 16 + (lane & 15);
        const int c = kt * 32 + (lane >> 4) * 8 + j;
        float v = 0.f;
        if (o < NO) v = offset_w[(o * CC + c) * 9 + k9];
        wsW[e] = f2bf(v);
    }
}

// ---- Kernel A: FUSED conv(MFMA) + coef + sample, one block per (b,h) ------
// 1024 thr = 16 waves. Phase 1: R12-verified MFMA shift-GEMM (B-frags from
// global xb). Phase 1b: coefs -> LDS planes (no global round-trip). Phase 2:
// wave = 8 channels, lane = px; weight gathers as float4 from s_wT[16][132].
__global__ __launch_bounds__(1024) void conv_sample(
    const float* __restrict__ x,            // [B][C][H][W] fp32
    const unsigned short* __restrict__ xb,
    const unsigned short* __restrict__ wsW,
    const float* __restrict__ offset_b,
    const float* __restrict__ weight,       // [C][16]
    float* __restrict__ out)
{
    const int blk = blockIdx.x;             // b*56 + h
    const int b = blk / HH;
    const int h = blk - b * HH;
    const int t = threadIdx.x;
    const int lane = t & 63;
    const int wv = t >> 6;                  // 0..15

    __shared__ float    s_red[2][NO][W64];  // 9 KiB
    __shared__ float    s_cf[4][NK2][W64];  // 9 KiB  (4 planes: conflict-free)
    __shared__ unsigned s_id[NK2][W64];     // 2.25 KiB
    __shared__ float    s_wT[16][132];      // 8.25 KiB [j][c], 16B-aligned rows

    // stage transposed weight (covered by the phase-1 barrier)
    for (int i = t; i < 16 * CC; i += 1024) {
        const int c = i >> 4, j = i & 15;
        s_wT[j][c] = weight[c * 16 + j];
    }

    // ---------------- phase 1: MFMA offsets (R12-verified) -----------------
    const int nt  = wv & 3;
    const int mt  = (wv >> 2) & 1;
    const int kh  = wv >> 3;
    const int q   = lane >> 4;
    const int n15 = lane & 15;

    f32x4 acc = {0.f, 0.f, 0.f, 0.f};
    const int k9lo = kh ? 5 : 0;
    const int k9hi = kh ? 9 : 5;
    for (int k9 = k9lo; k9 < k9hi; ++k9) {
        const int ky = k9 / 3, kx = k9 - ky * 3;
        int col = nt * 16 + n15 + kx;
        col = col > 57 ? 57 : col;
        const unsigned short* bbase =
            xb + (((long)b * 58 + (h + ky)) * 58 + col) * CC + q * 8;
        const unsigned short* abase =
            wsW + ((long)(k9 * 2 + mt) * 4 * 64 + lane) * 8;
        #pragma unroll
        for (int kt = 0; kt < 4; ++kt) {
            short8 a  = *(const short8*)(abase + kt * 512);
            short8 bf = *(const short8*)(bbase + kt * 32);
            acc = __builtin_amdgcn_mfma_f32_16x16x32_bf16(a, bf, acc, 0, 0, 0);
        }
    }
    #pragma unroll
    for (int reg = 0; reg < 4; ++reg) {
        const int o = mt * 16 + q * 4 + reg;
        if (o < NO) s_red[kh][o][nt * 16 + n15] = acc[reg];
    }
    __syncthreads();

    // ---------------- phase 1b: coefs into LDS planes ----------------------
    if (t < NK2 * 64) {
        const int k2 = t >> 6;
        const int px = t & 63;
        const float dy = s_red[0][2 * k2][px] + s_red[1][2 * k2][px]
                       + offset_b[2 * k2];
        const float dx = s_red[0][2 * k2 + 1][px] + s_red[1][2 * k2 + 1][px]
                       + offset_b[2 * k2 + 1];
        const float yc = dy + 0.5f + (float)(k2 / 3);
        const float xc = dx + 0.5f + (float)(k2 % 3);
        const float y0 = floorf(yc), x0f = floorf(xc);
        const float fy = yc - y0, fx = xc - x0f;
        const int yi = (int)y0, xi = (int)x0f;
        float cf[4]; int id[4];
        #pragma unroll
        for (int qq = 0; qq < 4; ++qq) {
            const int oy = qq >> 1, ox = qq & 1;
            const int yy = yi + oy, xx = xi + ox;
            float c2 = (oy ? fy : 1.f - fy) * (ox ? fx : 1.f - fx);
            const bool valid = (yy >= 0) && (yy < WSZ) && (xx >= 0) && (xx < WSZ);
            cf[qq] = valid ? c2 : 0.f;
            const int yyc = yy < 0 ? 0 : (yy > 3 ? 3 : yy);
            const int xxc = xx < 0 ? 0 : (xx > 3 ? 3 : xx);
            id[qq] = yyc * 4 + xxc;
        }
        s_cf[0][k2][px] = cf[0];
        s_cf[1][k2][px] = cf[1];
        s_cf[2][k2][px] = cf[2];
        s_cf[3][k2][px] = cf[3];
        s_id[k2][px] = (unsigned)(id[0] | (id[1] << 4) | (id[2] << 8) | (id[3] << 12));
    }
    __syncthreads();

    // ---------------- phase 2: sample + patch multiply ---------------------
    if (lane < WW) {
        const int px = lane;
        const int c0 = __builtin_amdgcn_readfirstlane(wv) * 8;
        #pragma unroll
        for (int sub = 0; sub < 2; ++sub) {
            const int cb = c0 + sub * 4;
            float xv[4][9];
            #pragma unroll
            for (int u = 0; u < 4; ++u) {
                const int c = cb + u;
                const float* xc = x + ((long)b * CC + c) * HH * WW;
                #pragma unroll
                for (int ky = 0; ky < 3; ++ky) {
                    const int hy = h + ky - 1;
                    #pragma unroll
                    for (int kx = 0; kx < 3; ++kx) {
                        const int wx = px + kx - 1;
                        float v = 0.f;
                        if (hy >= 0 && hy < HH && wx >= 0 && wx < WW)
                            v = xc[hy * WW + wx];
                        xv[u][ky * 3 + kx] = v;
                    }
                }
            }
            float res[4] = {0.f, 0.f, 0.f, 0.f};
            #pragma unroll
            for (int k2 = 0; k2 < NK2; ++k2) {
                const unsigned p = s_id[k2][px];
                const float c0f = s_cf[0][k2][px];
                const float c1f = s_cf[1][k2][px];
                const float c2f = s_cf[2][k2][px];
                const float c3f = s_cf[3][k2][px];
                const float4 W0 = *(const float4*)&s_wT[p & 15][cb];
                const float4 W1 = *(const float4*)&s_wT[(p >> 4) & 15][cb];
                const float4 W2 = *(const float4*)&s_wT[(p >> 8) & 15][cb];
                const float4 W3 = *(const float4*)&s_wT[(p >> 12) & 15][cb];
                res[0] += (c0f * W0.x + c1f * W1.x + c2f * W2.x + c3f * W3.x) * xv[0][k2];
                res[1] += (c0f * W0.y + c1f * W1.y + c2f * W2.y + c3f * W3.y) * xv[1][k2];
                res[2] += (c0f * W0.z + c1f * W1.z + c2f * W2.z + c3f * W3.z) * xv[2][k2];
                res[3] += (c0f * W0.w + c1f * W1.w + c2f * W2.w + c3f * W3.w) * xv[3][k2];
            }
            #pragma unroll
            for (int u = 0; u < 4; ++u) {
                const int c = cb + u;
                out[(((long)b * CC + c) * HH + h) * WW + px] = res[u];
            }
        }
    }
}

extern "C" void kernel_launch(void* const* d_in, const int* in_sizes, int n_in,
                              void* d_out, int out_size, void* d_ws, size_t ws_size,
                              hipStream_t stream) {
    const float* x        = (const float*)d_in[0];
    const float* offset_w = (const float*)d_in[1];
    const float* offset_b = (const float*)d_in[2];
    const float* weight   = (const float*)d_in[3];
    float* out = (float*)d_out;

    char* p = (char*)d_ws;
    unsigned short* wsW = (unsigned short*)p;           p += WSW_SHORTS * 2;
    unsigned short* xb  = (unsigned short*)p;

    prep       <<<232 + 144, 256, 0, stream>>>(x, offset_w, xb, wsW);
    conv_sample<<<4 * HH, 1024, 0, stream>>>(x, xb, wsW, offset_b, weight, out);
}